// Round 5
// baseline (73.657 us; speedup 1.0000x reference)
//
#include <hip/hip_runtime.h>

#define N 1024
#define D 128
#define PAD 132   // 128+4: rows 16B-aligned (528 B), bank stride 4 -> 2-way (free)

// ---------------------------------------------------------------------------
// Phase A: E[i][j] = exp(relu(sum_d |x[i][d]-x[j][d]| * w[d] + bias)), plus
// per-block row partials part[row][bx] (every slot written -> poisoned ws
// needs no init, no atomics).
//
// ROUND-5 CHANGE: manual register double-buffer (software pipeline, 1 chunk
// ahead). R4 diagnosis: every FMA in a chunk depends on ~all 7 ds_reads, and
// the compiler (VGPR=76) never hoisted next-chunk loads above current-chunk
// FMAs -> each wave stalls ~120+ cyc per chunk on lgkmcnt with neither pipe
// saturated (VALU ~22%, LDS ~43%). Two named buffer sets (static indexing)
// issue chunk k+1's loads before chunk k's FMAs; the 128-cyc FMA window
// covers ds latency. ds addresses become base + compile-time immediate.
//
// Geometry (proven R4): 64x32 tile, 512 thr = 2 d-groups x 256, micro 4x2,
// grid 512 -> 2 blocks/CU, 4 waves/SIMD, LDS 50 KB/block.
// ---------------------------------------------------------------------------

__device__ __forceinline__ void load_chunk(
    const float* __restrict__ ai, const float* __restrict__ bj,
    const float* __restrict__ wp, int dc,
    float4* __restrict__ A, float4* __restrict__ B, float4* __restrict__ W) {
  const int off = dc * 4;   // compile-time under full unroll -> imm offsets
  #pragma unroll
  for (int a = 0; a < 4; ++a)
    A[a] = *reinterpret_cast<const float4*>(ai + a * 16 * PAD + off);
  #pragma unroll
  for (int b = 0; b < 2; ++b)
    B[b] = *reinterpret_cast<const float4*>(bj + b * 16 * PAD + off);
  *W = *reinterpret_cast<const float4*>(wp + off);
}

__device__ __forceinline__ void fma_chunk(
    const float4* __restrict__ A, const float4* __restrict__ B,
    const float4 W, float acc[4][2]) {
  #pragma unroll
  for (int a = 0; a < 4; ++a) {
    #pragma unroll
    for (int b = 0; b < 2; ++b) {
      float v = acc[a][b];
      v = fmaf(fabsf(A[a].x - B[b].x), W.x, v);
      v = fmaf(fabsf(A[a].y - B[b].y), W.y, v);
      v = fmaf(fabsf(A[a].z - B[b].z), W.z, v);
      v = fmaf(fabsf(A[a].w - B[b].w), W.w, v);
      acc[a][b] = v;
    }
  }
}

__global__ __launch_bounds__(512, 4) void scores_kernel(
    const float* __restrict__ x, const float* __restrict__ w,
    const float* __restrict__ bias, float* __restrict__ E,
    float* __restrict__ part) {
  __shared__ float sxi[64 * PAD];   // 33.8 KB; combine buffer aliases this
  __shared__ float sxj[32 * PAD];   // 16.9 KB
  __shared__ float sw[D];           // 512 B

  const int t  = threadIdx.x;
  const int bi = blockIdx.y * 64;
  const int bj = blockIdx.x * 32;

  // ---- stage tiles + w: coalesced float4, one barrier ----------------------
  {
    const int c  = t & 31;
    const int r0 = t >> 5;   // 0..15
    #pragma unroll
    for (int p = 0; p < 4; ++p) {   // 64 rows of xi
      const int r = r0 + p * 16;
      const float4 v = reinterpret_cast<const float4*>(x)[(bi + r) * 32 + c];
      *reinterpret_cast<float4*>(&sxi[r * PAD + c * 4]) = v;
    }
    #pragma unroll
    for (int p = 0; p < 2; ++p) {   // 32 rows of xj
      const int r = r0 + p * 16;
      const float4 v = reinterpret_cast<const float4*>(x)[(bj + r) * 32 + c];
      *reinterpret_cast<float4*>(&sxj[r * PAD + c * 4]) = v;
    }
    if (t < 32)
      *reinterpret_cast<float4*>(&sw[t * 4]) =
          reinterpret_cast<const float4*>(w)[t];
  }
  __syncthreads();

  // d-group: wave-uniform (waves 0-3 -> g=0, waves 4-7 -> g=1)
  const int g  = __builtin_amdgcn_readfirstlane(t >> 8);   // 0..1
  const int s  = t & 255;
  const int tx = s & 15;   // cols tx + 16*b, b=0..1
  const int ty = s >> 4;   // rows ty + 16*a, a=0..3
  const int d0 = g * 64;

  float acc[4][2];
  #pragma unroll
  for (int a = 0; a < 4; ++a)
    #pragma unroll
    for (int b = 0; b < 2; ++b) acc[a][b] = 0.f;

  const float* ai = &sxi[ty * PAD + d0];
  const float* bjp = &sxj[tx * PAD + d0];
  const float* wp = &sw[d0];

  // ---- software-pipelined d-loop: load k+1 before computing k --------------
  float4 A0[4], B0[2], W0;
  float4 A1[4], B1[2], W1;
  load_chunk(ai, bjp, wp, 0, A0, B0, &W0);

  #pragma unroll
  for (int dc = 0; dc < 16; dc += 2) {
    load_chunk(ai, bjp, wp, dc + 1, A1, B1, &W1);   // issue ahead
    fma_chunk(A0, B0, W0, acc);
    if (dc + 2 < 16) load_chunk(ai, bjp, wp, dc + 2, A0, B0, &W0);
    fma_chunk(A1, B1, W1, acc);
  }
  __syncthreads();   // tiles dead; sxi becomes the combine buffer

  // ---- combine the 2 d-partials: g1 writes, g0 sums ------------------------
  float* comb = sxi;   // layout [256][9]: odd stride -> 2-way alias (free)
  if (g == 1) {
    float* dst = comb + s * 9;
    #pragma unroll
    for (int k = 0; k < 8; ++k) dst[k] = acc[k >> 1][k & 1];
  }
  __syncthreads();

  if (g == 0) {
    const float* src = comb + s * 9;
    #pragma unroll
    for (int k = 0; k < 8; ++k) acc[k >> 1][k & 1] += src[k];

    // ---- epilogue: bias + relu + exp (no max-sub: scores >= 0, bounded,
    // fp32-safe; identical numerics passed rounds 2-4, absmax 0.0) ----------
    const float bv = bias[0];
    #pragma unroll
    for (int a = 0; a < 4; ++a) {
      float p = 0.f;
      #pragma unroll
      for (int b = 0; b < 2; ++b) {
        const float ev = __expf(fmaxf(acc[a][b] + bv, 0.f));
        acc[a][b] = ev;
        p += ev;
      }
      #pragma unroll
      for (int o = 1; o < 16; o <<= 1) p += __shfl_xor(p, o, 64);
      if (tx == 0) part[(bi + ty + 16 * a) * 32 + blockIdx.x] = p;
    }

    #pragma unroll
    for (int a = 0; a < 4; ++a) {
      const int row = bi + ty + 16 * a;
      #pragma unroll
      for (int b = 0; b < 2; ++b)
        E[row * N + bj + tx + 16 * b] = acc[a][b];
    }
  }
}

// ---------------------------------------------------------------------------
// Phase B: scale pass. One block per row: sum 32 partials (L2-hot), scale.
// ---------------------------------------------------------------------------
__global__ __launch_bounds__(256) void scale_kernel(
    float* __restrict__ S, const float* __restrict__ part) {
  const int row = blockIdx.x;
  const int t   = threadIdx.x;

  float p = part[row * 32 + (t & 31)];
  #pragma unroll
  for (int o = 1; o < 32; o <<= 1) p += __shfl_xor(p, o, 64);
  const float r = 1.0f / p;

  float4* rowp = reinterpret_cast<float4*>(S + row * N);
  float4 v = rowp[t];
  v.x *= r; v.y *= r; v.z *= r; v.w *= r;
  rowp[t] = v;
}

extern "C" void kernel_launch(void* const* d_in, const int* in_sizes, int n_in,
                              void* d_out, int out_size, void* d_ws, size_t ws_size,
                              hipStream_t stream) {
  const float* x = (const float*)d_in[0];
  const float* w = (const float*)d_in[1];
  const float* b = (const float*)d_in[2];
  float* out  = (float*)d_out;
  float* part = (float*)d_ws;   // [1024][32] f32 = 128 KB, every slot written

  dim3 grid(N / 32, N / 64);    // (32,16) = 512 blocks, 2/CU, 4 waves/SIMD
  scores_kernel<<<grid, 512, 0, stream>>>(x, w, b, out, part);
  scale_kernel<<<N, 256, 0, stream>>>(out, part);
}